// Round 1
// baseline (541.983 us; speedup 1.0000x reference)
//
#include <hip/hip_runtime.h>
#include <stdint.h>
#include <stddef.h>

// ---------------------------------------------------------------------------
// CausalSelfAttention forward, MI355X/gfx950.
// Pipeline: cvt(fp32->bf16) -> GEMM1(qkv) -> norm+rope+transpose -> flash attn
//           -> GEMM2(out proj, fp32)
// ---------------------------------------------------------------------------

typedef __attribute__((ext_vector_type(8))) __bf16 bf16x8;
typedef __attribute__((ext_vector_type(4))) __bf16 bf16x4;
typedef __attribute__((ext_vector_type(4))) float  f32x4;

#define NB 2
#define NT 2048
#define NC 1536
#define NH 16
#define ND 96
#define NQKV 4608          // 3*NC
#define NM 4096            // NB*NT

static __device__ __forceinline__ float fexp2(float x) {
#if __has_builtin(__builtin_amdgcn_exp2f)
  return __builtin_amdgcn_exp2f(x);
#else
  return exp2f(x);
#endif
}

// async global->LDS, 16B per lane; LDS dest = wave-uniform base + lane*16
static __device__ __forceinline__ void g2lds16(const void* g, void* l) {
  __builtin_amdgcn_global_load_lds(
      (const __attribute__((address_space(1))) void*)g,
      (__attribute__((address_space(3))) void*)l, 16, 0, 0);
}

// ---------------------------------------------------------------------------
// fp32 -> bf16 conversion (vectorized 4-wide)
// ---------------------------------------------------------------------------
__global__ __launch_bounds__(256) void cvt_f32_bf16(
    const float4* __restrict__ src, bf16x4* __restrict__ dst, int n4) {
  int i = blockIdx.x * 256 + threadIdx.x;
  if (i < n4) {
    float4 v = src[i];
    bf16x4 o;
    o[0] = (__bf16)v.x; o[1] = (__bf16)v.y;
    o[2] = (__bf16)v.z; o[3] = (__bf16)v.w;
    dst[i] = o;
  }
}

// ---------------------------------------------------------------------------
// GEMM: C[m][n] = sum_k A[m][k] * B[n][k]   (A: MxK bf16, B: NxK bf16)
// 128x128 tile, BK=32, 4 waves (2x2), each wave 64x64 via 4x4 mfma 16x16x32.
// m97 structure: global_load_lds width16 staging, 2-barrier K-loop.
// Writes either f32 (Cf) or bf16 (Cb).
// ---------------------------------------------------------------------------
__global__ __launch_bounds__(256) void gemm_bt(
    const __bf16* __restrict__ A, const __bf16* __restrict__ Bw,
    float* __restrict__ Cf, __bf16* __restrict__ Cb, int M, int N, int K) {
  __shared__ __align__(16) __bf16 Al[128 * 32];
  __shared__ __align__(16) __bf16 Bl[128 * 32];
  const int tid = threadIdx.x;
  const int l   = tid & 63;
  const int w   = tid >> 6;
  const int m0  = blockIdx.y * 128;
  const int n0  = blockIdx.x * 128;
  const int wm  = (w >> 1) * 64;
  const int wn  = (w & 1) * 64;
  const int lm  = l & 15;
  const int lq  = l >> 4;
  // staging: lane covers 16B chunk; wave chunk = 1KB = 16 rows of 64B
  const int srow = l >> 2;          // row within wave chunk
  const int scol = (l & 3) * 8;     // bf16 element offset in row

  f32x4 acc[4][4] = {};

  for (int k0 = 0; k0 < K; k0 += 32) {
#pragma unroll
    for (int rd = 0; rd < 2; ++rd) {
      const int row = rd * 64 + w * 16 + srow;
      const int lof = rd * 4096 + w * 1024;
      g2lds16(A  + (size_t)(m0 + row) * K + k0 + scol, (char*)Al + lof);
      g2lds16(Bw + (size_t)(n0 + row) * K + k0 + scol, (char*)Bl + lof);
    }
    __syncthreads();
    bf16x8 af[4], bfr[4];
#pragma unroll
    for (int mi = 0; mi < 4; ++mi)
      af[mi] = *(const bf16x8*)(Al + (wm + mi * 16 + lm) * 32 + lq * 8);
#pragma unroll
    for (int ni = 0; ni < 4; ++ni)
      bfr[ni] = *(const bf16x8*)(Bl + (wn + ni * 16 + lm) * 32 + lq * 8);
#pragma unroll
    for (int mi = 0; mi < 4; ++mi)
#pragma unroll
      for (int ni = 0; ni < 4; ++ni)
        acc[mi][ni] = __builtin_amdgcn_mfma_f32_16x16x32_bf16(
            af[mi], bfr[ni], acc[mi][ni], 0, 0, 0);
    __syncthreads();
  }

  // epilogue: C/D layout col=lane&15, row=(lane>>4)*4+r  (m89/m91 verified)
  const int r0 = lq * 4;
#pragma unroll
  for (int mi = 0; mi < 4; ++mi)
#pragma unroll
    for (int ni = 0; ni < 4; ++ni)
#pragma unroll
      for (int r = 0; r < 4; ++r) {
        const size_t row = (size_t)(m0 + wm + mi * 16 + r0 + r);
        const size_t col = (size_t)(n0 + wn + ni * 16 + lm);
        if (Cf) Cf[row * N + col] = acc[mi][ni][r];
        else    Cb[row * N + col] = (__bf16)acc[mi][ni][r];
      }
}

// ---------------------------------------------------------------------------
// qk RMS-norm + 3D RoPE + layout transform.
// In : qkv (B*T, 4608) bf16  [q|k|v, each (H,D) inner]
// Out: q,k (B,H,T,D) bf16; vT (B,H,D,T) bf16
// One wave per (b,t,h): lane covers d=l and d=64+l (l<32).
// ---------------------------------------------------------------------------
static __device__ __forceinline__ float rope_one(float v, float p, int d,
                                                 const float* c3) {
  const int a  = d >> 5;        // which of 3 coord axes (d3=32)
  const int j  = d & 31;
  const int jj = j & 15;        // half=16
  // inv_freq = 10000^(-jj/16) = exp2(-jj * log2(10000)/16)
  const float invf = fexp2((float)jj * -0.8304820237218406f);
  const float ang  = c3[a] * invf;
  float sn, cs;
  __sincosf(ang, &sn, &cs);
  return (j < 16) ? (v * cs - p * sn) : (v * cs + p * sn);
}

__global__ __launch_bounds__(256) void normrope_kernel(
    const __bf16* __restrict__ qkv, const float* __restrict__ coords,
    const int* __restrict__ ttype, const float* __restrict__ qsc,
    const float* __restrict__ ksc, __bf16* __restrict__ qo,
    __bf16* __restrict__ ko, __bf16* __restrict__ vo) {
  const int l   = threadIdx.x & 63;
  const int w   = threadIdx.x >> 6;
  const int rid = blockIdx.x * 4 + w;       // (b*T+t)*H + h
  const int h   = rid & (NH - 1);
  const int bt  = rid >> 4;
  const int t   = bt & (NT - 1);
  const int b   = bt >> 11;                 // T = 2048
  const __bf16* base = qkv + (size_t)bt * NQKV + h * ND;
  const float*  c3   = coords + (size_t)bt * 3;
  const bool rope    = ttype[bt] > 0;
  const size_t bh    = (size_t)(b * NH + h);

  // ---- q ----
  {
    float x0 = (float)base[l];
    float x1 = (l < 32) ? (float)base[64 + l] : 0.f;
    float ss = x0 * x0 + x1 * x1;
#pragma unroll
    for (int off = 1; off < 64; off <<= 1) ss += __shfl_xor(ss, off, 64);
    const float rn = rsqrtf(ss * (1.f / 96.f) + 1e-6f);
    x0 *= rn * qsc[l];
    if (l < 32) x1 *= rn * qsc[64 + l];
    const float p0 = __shfl_xor(x0, 16, 64);
    const float p1 = __shfl_xor(x1, 16, 64);
    if (rope) {
      x0 = rope_one(x0, p0, l, c3);
      if (l < 32) x1 = rope_one(x1, p1, 64 + l, c3);
    }
    __bf16* dst = qo + (bh * NT + t) * ND;
    dst[l] = (__bf16)x0;
    if (l < 32) dst[64 + l] = (__bf16)x1;
  }
  // ---- k ----
  {
    float x0 = (float)base[NC + l];
    float x1 = (l < 32) ? (float)base[NC + 64 + l] : 0.f;
    float ss = x0 * x0 + x1 * x1;
#pragma unroll
    for (int off = 1; off < 64; off <<= 1) ss += __shfl_xor(ss, off, 64);
    const float rn = rsqrtf(ss * (1.f / 96.f) + 1e-6f);
    x0 *= rn * ksc[l];
    if (l < 32) x1 *= rn * ksc[64 + l];
    const float p0 = __shfl_xor(x0, 16, 64);
    const float p1 = __shfl_xor(x1, 16, 64);
    if (rope) {
      x0 = rope_one(x0, p0, l, c3);
      if (l < 32) x1 = rope_one(x1, p1, 64 + l, c3);
    }
    __bf16* dst = ko + (bh * NT + t) * ND;
    dst[l] = (__bf16)x0;
    if (l < 32) dst[64 + l] = (__bf16)x1;
  }
  // ---- v (transpose only) ----
  {
    vo[(bh * ND + l) * NT + t] = base[2 * NC + l];
    if (l < 32) vo[(bh * ND + 64 + l) * NT + t] = base[2 * NC + 64 + l];
  }
}

// ---------------------------------------------------------------------------
// Flash-style causal attention.
// q,k: (B,H,T,D) bf16; vT: (B,H,D,T) bf16; out: (B,T,H,D)=(B*T, C) bf16.
// Block = 64 q-rows (4 waves x 16 rows), grid (T/64, B*H).
// Per 32-key tile: QK^T via 6 mfma 16x16x32, online softmax (shfl row
// reduce), P->LDS (per-wave scratch) -> A-frag, PV via 6 mfma.
// No __syncthreads: waves fully independent (per-wave causal trip count).
// ---------------------------------------------------------------------------
__global__ __launch_bounds__(256) void attn_fwd(
    const __bf16* __restrict__ q, const __bf16* __restrict__ k,
    const __bf16* __restrict__ vt, __bf16* __restrict__ out) {
  // per-wave P scratch, rows padded to 40 bf16 (80B, stride 20 banks)
  __shared__ __align__(16) __bf16 plds[4][16][40];
  const int tid = threadIdx.x;
  const int l   = tid & 63;
  const int w   = tid >> 6;
  const int bh  = blockIdx.y;
  const int qt  = gridDim.x - 1 - blockIdx.x;   // launch big tiles first
  const int q0  = qt * 64;
  const int m0  = q0 + w * 16;
  const int lm  = l & 15;
  const int lq  = l >> 4;
  const __bf16* qh = q  + (size_t)bh * NT * ND;
  const __bf16* kh = k  + (size_t)bh * NT * ND;
  const __bf16* vh = vt + (size_t)bh * ND * NT;

  bf16x8 aq[3];
#pragma unroll
  for (int c = 0; c < 3; ++c)
    aq[c] = *(const bf16x8*)(qh + (size_t)(m0 + lm) * ND + c * 32 + lq * 8);

  f32x4 o[6] = {};
  float mrow[4], lrow[4];
#pragma unroll
  for (int r = 0; r < 4; ++r) { mrow[r] = -1e30f; lrow[r] = 0.f; }
  const float cl = 0.10206207261596575f * 1.4426950408889634f; // scale*log2e

  const int nkt = ((m0 + 15) >> 5) + 1;   // per-wave causal bound
  for (int kt = 0; kt < nkt; ++kt) {
    const int n0 = kt * 32;
    f32x4 s[2];
#pragma unroll
    for (int nt = 0; nt < 2; ++nt) {
      f32x4 a = {};
#pragma unroll
      for (int c = 0; c < 3; ++c) {
        bf16x8 bk = *(const bf16x8*)(kh + (size_t)(n0 + nt * 16 + lm) * ND +
                                     c * 32 + lq * 8);
        a = __builtin_amdgcn_mfma_f32_16x16x32_bf16(aq[c], bk, a, 0, 0, 0);
      }
      s[nt] = a;
    }
    // causal mask (only diagonal-straddling tiles)
    if (n0 + 31 > m0) {
#pragma unroll
      for (int nt = 0; nt < 2; ++nt)
#pragma unroll
        for (int r = 0; r < 4; ++r)
          if (n0 + nt * 16 + lm > m0 + lq * 4 + r) s[nt][r] = -1e30f;
    }
    // row max across 16 cols (lanes sharing lq group)
    float mx[4];
#pragma unroll
    for (int r = 0; r < 4; ++r) mx[r] = fmaxf(s[0][r], s[1][r]);
#pragma unroll
    for (int off = 1; off < 16; off <<= 1)
#pragma unroll
      for (int r = 0; r < 4; ++r) mx[r] = fmaxf(mx[r], __shfl_xor(mx[r], off, 64));
    float al[4];
#pragma unroll
    for (int r = 0; r < 4; ++r) {
      const float mn = fmaxf(mrow[r], mx[r]);
      al[r]   = fexp2((mrow[r] - mn) * cl);
      mrow[r] = mn;
    }
    // p = exp2((s-m)*cl); row-sum
    float ps[4];
#pragma unroll
    for (int nt = 0; nt < 2; ++nt)
#pragma unroll
      for (int r = 0; r < 4; ++r)
        s[nt][r] = fexp2((s[nt][r] - mrow[r]) * cl);
#pragma unroll
    for (int r = 0; r < 4; ++r) ps[r] = s[0][r] + s[1][r];
#pragma unroll
    for (int off = 1; off < 16; off <<= 1)
#pragma unroll
      for (int r = 0; r < 4; ++r) ps[r] += __shfl_xor(ps[r], off, 64);
#pragma unroll
    for (int r = 0; r < 4; ++r) lrow[r] = lrow[r] * al[r] + ps[r];
    // rescale O
#pragma unroll
    for (int dt = 0; dt < 6; ++dt)
#pragma unroll
      for (int r = 0; r < 4; ++r) o[dt][r] *= al[r];
    // P: C-layout -> LDS -> A-layout (m120-verified round trip)
#pragma unroll
    for (int nt = 0; nt < 2; ++nt)
#pragma unroll
      for (int r = 0; r < 4; ++r)
        plds[w][lq * 4 + r][nt * 16 + lm] = (__bf16)s[nt][r];
    bf16x8 ap = *(const bf16x8*)(&plds[w][lm][lq * 8]);
    // O += P * V
#pragma unroll
    for (int dt = 0; dt < 6; ++dt) {
      bf16x8 bv = *(const bf16x8*)(vh + (size_t)(dt * 16 + lm) * NT + n0 + lq * 8);
      o[dt] = __builtin_amdgcn_mfma_f32_16x16x32_bf16(ap, bv, o[dt], 0, 0, 0);
    }
  }
  // epilogue: out[(b*T+t), h*96+d]
  const int b = bh >> 4, h = bh & 15;
  float rl[4];
#pragma unroll
  for (int r = 0; r < 4; ++r) rl[r] = 1.f / lrow[r];
#pragma unroll
  for (int dt = 0; dt < 6; ++dt)
#pragma unroll
    for (int r = 0; r < 4; ++r) {
      const int t = m0 + lq * 4 + r;
      out[((size_t)(b * NT + t)) * NC + h * ND + dt * 16 + lm] =
          (__bf16)(o[dt][r] * rl[r]);
    }
}

// ---------------------------------------------------------------------------
// workspace layout (bytes); attn-out aliases xb (dead after GEMM1)
// ---------------------------------------------------------------------------
static constexpr size_t OFF_XB   = 0;          // 12,582,912  (also attn out)
static constexpr size_t OFF_WQKV = 12582912;   // 14,155,776
static constexpr size_t OFF_WOUT = 26738688;   //  4,718,592
static constexpr size_t OFF_QKV  = 31457280;   // 37,748,736
static constexpr size_t OFF_Q    = 69206016;   // 12,582,912
static constexpr size_t OFF_K    = 81788928;   // 12,582,912
static constexpr size_t OFF_VT   = 94371840;   // 12,582,912  -> end 106,954,752

extern "C" void kernel_launch(void* const* d_in, const int* in_sizes, int n_in,
                              void* d_out, int out_size, void* d_ws,
                              size_t ws_size, hipStream_t stream) {
  const float* x      = (const float*)d_in[0];
  const float* coords = (const float*)d_in[1];
  const int*   ttype  = (const int*)d_in[2];
  const float* wqkv   = (const float*)d_in[3];
  const float* wout   = (const float*)d_in[4];
  const float* qs     = (const float*)d_in[5];
  const float* ks     = (const float*)d_in[6];

  char* ws = (char*)d_ws;
  __bf16* xb    = (__bf16*)(ws + OFF_XB);
  __bf16* wqkvb = (__bf16*)(ws + OFF_WQKV);
  __bf16* woutb = (__bf16*)(ws + OFF_WOUT);
  __bf16* qkvb  = (__bf16*)(ws + OFF_QKV);
  __bf16* qb    = (__bf16*)(ws + OFF_Q);
  __bf16* kb    = (__bf16*)(ws + OFF_K);
  __bf16* vtb   = (__bf16*)(ws + OFF_VT);
  __bf16* attnb = (__bf16*)(ws + OFF_XB);   // alias

  // 1. fp32 -> bf16 conversions
  {
    const int n4x = NM * NC / 4;            // 1,572,864
    const int n4w = NQKV * NC / 4;          // 1,769,472
    const int n4o = NC * NC / 4;            //   589,824
    cvt_f32_bf16<<<(n4x + 255) / 256, 256, 0, stream>>>(
        (const float4*)x, (bf16x4*)xb, n4x);
    cvt_f32_bf16<<<(n4w + 255) / 256, 256, 0, stream>>>(
        (const float4*)wqkv, (bf16x4*)wqkvb, n4w);
    cvt_f32_bf16<<<(n4o + 255) / 256, 256, 0, stream>>>(
        (const float4*)wout, (bf16x4*)woutb, n4o);
  }
  // 2. qkv = x @ W_qkv^T  (bf16 out)
  gemm_bt<<<dim3(NQKV / 128, NM / 128), 256, 0, stream>>>(
      xb, wqkvb, nullptr, qkvb, NM, NQKV, NC);
  // 3. qk-norm + rope + v-transpose
  normrope_kernel<<<(NB * NT * NH) / 4, 256, 0, stream>>>(
      qkvb, coords, ttype, qs, ks, qb, kb, vtb);
  // 4. causal attention
  attn_fwd<<<dim3(NT / 64, NB * NH), 256, 0, stream>>>(qb, kb, vtb, attnb);
  // 5. out = attn @ W_out^T (fp32 out)
  gemm_bt<<<dim3(NC / 128, NM / 128), 256, 0, stream>>>(
      attnb, woutb, (float*)d_out, nullptr, NM, NC, NC);
}

// Round 2
// 418.076 us; speedup vs baseline: 1.2964x; 1.2964x over previous
//
#include <hip/hip_runtime.h>
#include <stdint.h>
#include <stddef.h>

// ---------------------------------------------------------------------------
// CausalSelfAttention forward, MI355X/gfx950.
// Pipeline: cvt(fp32->bf16) -> GEMM1(qkv) -> norm+rope+transpose -> flash attn
//           -> GEMM2(out proj, fp32)
// R2: attn rewritten with FIXED-max softmax (|q.k| <= 96 by Cauchy-Schwarz
//     after RMS-norm) -> no per-tile reductions / rescaling on the critical
//     path; 32 q-rows per wave as two mirrored 16-row frags (causal balance).
// ---------------------------------------------------------------------------

typedef __attribute__((ext_vector_type(8))) __bf16 bf16x8;
typedef __attribute__((ext_vector_type(4))) __bf16 bf16x4;
typedef __attribute__((ext_vector_type(4))) float  f32x4;

#define NB 2
#define NT 2048
#define NC 1536
#define NH 16
#define ND 96
#define NQKV 4608          // 3*NC
#define NM 4096            // NB*NT

static __device__ __forceinline__ float fexp2(float x) {
#if __has_builtin(__builtin_amdgcn_exp2f)
  return __builtin_amdgcn_exp2f(x);
#else
  return exp2f(x);
#endif
}

// async global->LDS, 16B per lane; LDS dest = wave-uniform base + lane*16
static __device__ __forceinline__ void g2lds16(const void* g, void* l) {
  __builtin_amdgcn_global_load_lds(
      (const __attribute__((address_space(1))) void*)g,
      (__attribute__((address_space(3))) void*)l, 16, 0, 0);
}

// ---------------------------------------------------------------------------
// fp32 -> bf16 conversion (vectorized 4-wide)
// ---------------------------------------------------------------------------
__global__ __launch_bounds__(256) void cvt_f32_bf16(
    const float4* __restrict__ src, bf16x4* __restrict__ dst, int n4) {
  int i = blockIdx.x * 256 + threadIdx.x;
  if (i < n4) {
    float4 v = src[i];
    bf16x4 o;
    o[0] = (__bf16)v.x; o[1] = (__bf16)v.y;
    o[2] = (__bf16)v.z; o[3] = (__bf16)v.w;
    dst[i] = o;
  }
}

// ---------------------------------------------------------------------------
// GEMM: C[m][n] = sum_k A[m][k] * B[n][k]   (A: MxK bf16, B: NxK bf16)
// 128x128 tile, BK=32, 4 waves (2x2), each wave 64x64 via 4x4 mfma 16x16x32.
// ---------------------------------------------------------------------------
__global__ __launch_bounds__(256) void gemm_bt(
    const __bf16* __restrict__ A, const __bf16* __restrict__ Bw,
    float* __restrict__ Cf, __bf16* __restrict__ Cb, int M, int N, int K) {
  __shared__ __align__(16) __bf16 Al[128 * 32];
  __shared__ __align__(16) __bf16 Bl[128 * 32];
  const int tid = threadIdx.x;
  const int l   = tid & 63;
  const int w   = tid >> 6;
  const int m0  = blockIdx.y * 128;
  const int n0  = blockIdx.x * 128;
  const int wm  = (w >> 1) * 64;
  const int wn  = (w & 1) * 64;
  const int lm  = l & 15;
  const int lq  = l >> 4;
  const int srow = l >> 2;          // row within wave chunk
  const int scol = (l & 3) * 8;     // bf16 element offset in row

  f32x4 acc[4][4] = {};

  for (int k0 = 0; k0 < K; k0 += 32) {
#pragma unroll
    for (int rd = 0; rd < 2; ++rd) {
      const int row = rd * 64 + w * 16 + srow;
      const int lof = rd * 4096 + w * 1024;
      g2lds16(A  + (size_t)(m0 + row) * K + k0 + scol, (char*)Al + lof);
      g2lds16(Bw + (size_t)(n0 + row) * K + k0 + scol, (char*)Bl + lof);
    }
    __syncthreads();
    bf16x8 af[4], bfr[4];
#pragma unroll
    for (int mi = 0; mi < 4; ++mi)
      af[mi] = *(const bf16x8*)(Al + (wm + mi * 16 + lm) * 32 + lq * 8);
#pragma unroll
    for (int ni = 0; ni < 4; ++ni)
      bfr[ni] = *(const bf16x8*)(Bl + (wn + ni * 16 + lm) * 32 + lq * 8);
#pragma unroll
    for (int mi = 0; mi < 4; ++mi)
#pragma unroll
      for (int ni = 0; ni < 4; ++ni)
        acc[mi][ni] = __builtin_amdgcn_mfma_f32_16x16x32_bf16(
            af[mi], bfr[ni], acc[mi][ni], 0, 0, 0);
    __syncthreads();
  }

  // epilogue: C/D layout col=lane&15, row=(lane>>4)*4+r  (m89/m91 verified)
  const int r0 = lq * 4;
#pragma unroll
  for (int mi = 0; mi < 4; ++mi)
#pragma unroll
    for (int ni = 0; ni < 4; ++ni)
#pragma unroll
      for (int r = 0; r < 4; ++r) {
        const size_t row = (size_t)(m0 + wm + mi * 16 + r0 + r);
        const size_t col = (size_t)(n0 + wn + ni * 16 + lm);
        if (Cf) Cf[row * N + col] = acc[mi][ni][r];
        else    Cb[row * N + col] = (__bf16)acc[mi][ni][r];
      }
}

// ---------------------------------------------------------------------------
// qk RMS-norm + 3D RoPE + layout transform.
// ---------------------------------------------------------------------------
static __device__ __forceinline__ float rope_one(float v, float p, int d,
                                                 const float* c3) {
  const int a  = d >> 5;        // which of 3 coord axes (d3=32)
  const int j  = d & 31;
  const int jj = j & 15;        // half=16
  const float invf = fexp2((float)jj * -0.8304820237218406f);
  const float ang  = c3[a] * invf;
  float sn, cs;
  __sincosf(ang, &sn, &cs);
  return (j < 16) ? (v * cs - p * sn) : (v * cs + p * sn);
}

__global__ __launch_bounds__(256) void normrope_kernel(
    const __bf16* __restrict__ qkv, const float* __restrict__ coords,
    const int* __restrict__ ttype, const float* __restrict__ qsc,
    const float* __restrict__ ksc, __bf16* __restrict__ qo,
    __bf16* __restrict__ ko, __bf16* __restrict__ vo) {
  const int l   = threadIdx.x & 63;
  const int w   = threadIdx.x >> 6;
  const int rid = blockIdx.x * 4 + w;       // (b*T+t)*H + h
  const int h   = rid & (NH - 1);
  const int bt  = rid >> 4;
  const int t   = bt & (NT - 1);
  const int b   = bt >> 11;                 // T = 2048
  const __bf16* base = qkv + (size_t)bt * NQKV + h * ND;
  const float*  c3   = coords + (size_t)bt * 3;
  const bool rope    = ttype[bt] > 0;
  const size_t bh    = (size_t)(b * NH + h);

  // ---- q ----
  {
    float x0 = (float)base[l];
    float x1 = (l < 32) ? (float)base[64 + l] : 0.f;
    float ss = x0 * x0 + x1 * x1;
#pragma unroll
    for (int off = 1; off < 64; off <<= 1) ss += __shfl_xor(ss, off, 64);
    const float rn = rsqrtf(ss * (1.f / 96.f) + 1e-6f);
    x0 *= rn * qsc[l];
    if (l < 32) x1 *= rn * qsc[64 + l];
    const float p0 = __shfl_xor(x0, 16, 64);
    const float p1 = __shfl_xor(x1, 16, 64);
    if (rope) {
      x0 = rope_one(x0, p0, l, c3);
      if (l < 32) x1 = rope_one(x1, p1, 64 + l, c3);
    }
    __bf16* dst = qo + (bh * NT + t) * ND;
    dst[l] = (__bf16)x0;
    if (l < 32) dst[64 + l] = (__bf16)x1;
  }
  // ---- k ----
  {
    float x0 = (float)base[NC + l];
    float x1 = (l < 32) ? (float)base[NC + 64 + l] : 0.f;
    float ss = x0 * x0 + x1 * x1;
#pragma unroll
    for (int off = 1; off < 64; off <<= 1) ss += __shfl_xor(ss, off, 64);
    const float rn = rsqrtf(ss * (1.f / 96.f) + 1e-6f);
    x0 *= rn * ksc[l];
    if (l < 32) x1 *= rn * ksc[64 + l];
    const float p0 = __shfl_xor(x0, 16, 64);
    const float p1 = __shfl_xor(x1, 16, 64);
    if (rope) {
      x0 = rope_one(x0, p0, l, c3);
      if (l < 32) x1 = rope_one(x1, p1, 64 + l, c3);
    }
    __bf16* dst = ko + (bh * NT + t) * ND;
    dst[l] = (__bf16)x0;
    if (l < 32) dst[64 + l] = (__bf16)x1;
  }
  // ---- v (transpose only) ----
  {
    vo[(bh * ND + l) * NT + t] = base[2 * NC + l];
    if (l < 32) vo[(bh * ND + 64 + l) * NT + t] = base[2 * NC + 64 + l];
  }
}

// ---------------------------------------------------------------------------
// Flash-style causal attention, fixed-max softmax.
// q,k: (B,H,T,D) bf16; vT: (B,H,D,T) bf16; out: (B,T,H,D)=(B*T, C) bf16.
// Grid (16, B*H); block = 4 waves. Each wave owns TWO 16-row q-frags at
// mirrored positions (qt*64+w*16 and (31-qt)*64+w*16) -> per-wave key work
// is ~constant (causal balance). Per 32-key tile: 6 QK mfma/frag, 8 exp2/
// frag, per-lane l partials (reduced once in epilogue), P->LDS->A-frag,
// 6 PV mfma/frag. No __syncthreads; no per-tile cross-lane ops.
// Fixed max: RMS-norm => |q.k| <= 96 (+bf16 eps), so p=exp2((s-96)*cl)<=1.1.
// ---------------------------------------------------------------------------
static __device__ __forceinline__ void attn_tile(
    const bf16x8 (&aq)[3], const bf16x8 (&bk)[2][3], int q0r, int n0,
    int lm, int lq, f32x4& lsum, __bf16* pbase /* 16 rows x 40 */) {
  f32x4 s[2];
#pragma unroll
  for (int nt = 0; nt < 2; ++nt) {
    f32x4 a = {};
#pragma unroll
    for (int c = 0; c < 3; ++c)
      a = __builtin_amdgcn_mfma_f32_16x16x32_bf16(aq[c], bk[nt][c], a, 0, 0, 0);
    s[nt] = a;
  }
  if (n0 + 31 > q0r) {   // diagonal-straddling tile: causal mask
#pragma unroll
    for (int nt = 0; nt < 2; ++nt)
#pragma unroll
      for (int r = 0; r < 4; ++r)
        if (n0 + nt * 16 + lm > q0r + lq * 4 + r) s[nt][r] = -1e30f;
  }
  const float cl = 0.10206207261596575f * 1.4426950408889634f;
#pragma unroll
  for (int nt = 0; nt < 2; ++nt)
#pragma unroll
    for (int r = 0; r < 4; ++r)
      s[nt][r] = fexp2((s[nt][r] - 96.0f) * cl);
#pragma unroll
  for (int r = 0; r < 4; ++r) lsum[r] += s[0][r] + s[1][r];
#pragma unroll
  for (int nt = 0; nt < 2; ++nt)
#pragma unroll
    for (int r = 0; r < 4; ++r)
      pbase[(lq * 4 + r) * 40 + nt * 16 + lm] = (__bf16)s[nt][r];
}

__global__ __launch_bounds__(256) void attn_fwd(
    const __bf16* __restrict__ q, const __bf16* __restrict__ k,
    const __bf16* __restrict__ vt, __bf16* __restrict__ out) {
  __shared__ __align__(16) __bf16 plds[4][32][40];
  const int tid = threadIdx.x;
  const int l   = tid & 63;
  const int w   = tid >> 6;
  const int bh  = blockIdx.y;
  const int qt  = blockIdx.x;               // 0..15
  const int lm  = l & 15;
  const int lq  = l >> 4;
  const int q0a = qt * 64 + w * 16;         // low-position frag
  const int q0b = (31 - qt) * 64 + w * 16;  // mirrored high-position frag
  const __bf16* qh = q  + (size_t)bh * NT * ND;
  const __bf16* kh = k  + (size_t)bh * NT * ND;
  const __bf16* vh = vt + (size_t)bh * ND * NT;
  __bf16* pb0 = &plds[w][0][0];
  __bf16* pb1 = &plds[w][16][0];

  bf16x8 aq0[3], aq1[3];
#pragma unroll
  for (int c = 0; c < 3; ++c) {
    aq0[c] = *(const bf16x8*)(qh + (size_t)(q0a + lm) * ND + c * 32 + lq * 8);
    aq1[c] = *(const bf16x8*)(qh + (size_t)(q0b + lm) * ND + c * 32 + lq * 8);
  }

  f32x4 o0[6] = {}, o1[6] = {};
  f32x4 ls0 = {}, ls1 = {};
  const int nkt0 = ((q0a + 15) >> 5) + 1;
  const int nkt1 = ((q0b + 15) >> 5) + 1;
  const int b = bh >> 4, h = bh & 15;

  int kt = 0;
  // phase 1: both frags active
  for (; kt < nkt0; ++kt) {
    const int n0 = kt * 32;
    bf16x8 bk[2][3];
#pragma unroll
    for (int nt = 0; nt < 2; ++nt)
#pragma unroll
      for (int c = 0; c < 3; ++c)
        bk[nt][c] = *(const bf16x8*)(kh + (size_t)(n0 + nt * 16 + lm) * ND +
                                     c * 32 + lq * 8);
    attn_tile(aq0, bk, q0a, n0, lm, lq, ls0, pb0);
    attn_tile(aq1, bk, q0b, n0, lm, lq, ls1, pb1);
    bf16x8 ap0 = *(const bf16x8*)(pb0 + lm * 40 + lq * 8);
    bf16x8 ap1 = *(const bf16x8*)(pb1 + lm * 40 + lq * 8);
#pragma unroll
    for (int dt = 0; dt < 6; ++dt) {
      bf16x8 bv = *(const bf16x8*)(vh + (size_t)(dt * 16 + lm) * NT + n0 + lq * 8);
      o0[dt] = __builtin_amdgcn_mfma_f32_16x16x32_bf16(ap0, bv, o0[dt], 0, 0, 0);
      o1[dt] = __builtin_amdgcn_mfma_f32_16x16x32_bf16(ap1, bv, o1[dt], 0, 0, 0);
    }
  }
  // frag0 epilogue now (frees its registers for phase 2)
  {
    float rl[4];
#pragma unroll
    for (int r = 0; r < 4; ++r) {
      float v = ls0[r];
#pragma unroll
      for (int off = 1; off < 16; off <<= 1) v += __shfl_xor(v, off, 64);
      rl[r] = 1.f / v;
    }
#pragma unroll
    for (int dt = 0; dt < 6; ++dt)
#pragma unroll
      for (int r = 0; r < 4; ++r) {
        const int t = q0a + lq * 4 + r;
        out[((size_t)(b * NT + t)) * NC + h * ND + dt * 16 + lm] =
            (__bf16)(o0[dt][r] * rl[r]);
      }
  }
  // phase 2: frag1 only
  for (; kt < nkt1; ++kt) {
    const int n0 = kt * 32;
    bf16x8 bk[2][3];
#pragma unroll
    for (int nt = 0; nt < 2; ++nt)
#pragma unroll
      for (int c = 0; c < 3; ++c)
        bk[nt][c] = *(const bf16x8*)(kh + (size_t)(n0 + nt * 16 + lm) * ND +
                                     c * 32 + lq * 8);
    attn_tile(aq1, bk, q0b, n0, lm, lq, ls1, pb1);
    bf16x8 ap1 = *(const bf16x8*)(pb1 + lm * 40 + lq * 8);
#pragma unroll
    for (int dt = 0; dt < 6; ++dt) {
      bf16x8 bv = *(const bf16x8*)(vh + (size_t)(dt * 16 + lm) * NT + n0 + lq * 8);
      o1[dt] = __builtin_amdgcn_mfma_f32_16x16x32_bf16(ap1, bv, o1[dt], 0, 0, 0);
    }
  }
  // frag1 epilogue
  {
    float rl[4];
#pragma unroll
    for (int r = 0; r < 4; ++r) {
      float v = ls1[r];
#pragma unroll
      for (int off = 1; off < 16; off <<= 1) v += __shfl_xor(v, off, 64);
      rl[r] = 1.f / v;
    }
#pragma unroll
    for (int dt = 0; dt < 6; ++dt)
#pragma unroll
      for (int r = 0; r < 4; ++r) {
        const int t = q0b + lq * 4 + r;
        out[((size_t)(b * NT + t)) * NC + h * ND + dt * 16 + lm] =
            (__bf16)(o1[dt][r] * rl[r]);
      }
  }
}

// ---------------------------------------------------------------------------
// workspace layout (bytes); attn-out aliases xb (dead after GEMM1)
// ---------------------------------------------------------------------------
static constexpr size_t OFF_XB   = 0;          // 12,582,912  (also attn out)
static constexpr size_t OFF_WQKV = 12582912;   // 14,155,776
static constexpr size_t OFF_WOUT = 26738688;   //  4,718,592
static constexpr size_t OFF_QKV  = 31457280;   // 37,748,736
static constexpr size_t OFF_Q    = 69206016;   // 12,582,912
static constexpr size_t OFF_K    = 81788928;   // 12,582,912
static constexpr size_t OFF_VT   = 94371840;   // 12,582,912  -> end 106,954,752

extern "C" void kernel_launch(void* const* d_in, const int* in_sizes, int n_in,
                              void* d_out, int out_size, void* d_ws,
                              size_t ws_size, hipStream_t stream) {
  const float* x      = (const float*)d_in[0];
  const float* coords = (const float*)d_in[1];
  const int*   ttype  = (const int*)d_in[2];
  const float* wqkv   = (const float*)d_in[3];
  const float* wout   = (const float*)d_in[4];
  const float* qs     = (const float*)d_in[5];
  const float* ks     = (const float*)d_in[6];

  char* ws = (char*)d_ws;
  __bf16* xb    = (__bf16*)(ws + OFF_XB);
  __bf16* wqkvb = (__bf16*)(ws + OFF_WQKV);
  __bf16* woutb = (__bf16*)(ws + OFF_WOUT);
  __bf16* qkvb  = (__bf16*)(ws + OFF_QKV);
  __bf16* qb    = (__bf16*)(ws + OFF_Q);
  __bf16* kb    = (__bf16*)(ws + OFF_K);
  __bf16* vtb   = (__bf16*)(ws + OFF_VT);
  __bf16* attnb = (__bf16*)(ws + OFF_XB);   // alias

  // 1. fp32 -> bf16 conversions
  {
    const int n4x = NM * NC / 4;            // 1,572,864
    const int n4w = NQKV * NC / 4;          // 1,769,472
    const int n4o = NC * NC / 4;            //   589,824
    cvt_f32_bf16<<<(n4x + 255) / 256, 256, 0, stream>>>(
        (const float4*)x, (bf16x4*)xb, n4x);
    cvt_f32_bf16<<<(n4w + 255) / 256, 256, 0, stream>>>(
        (const float4*)wqkv, (bf16x4*)wqkvb, n4w);
    cvt_f32_bf16<<<(n4o + 255) / 256, 256, 0, stream>>>(
        (const float4*)wout, (bf16x4*)woutb, n4o);
  }
  // 2. qkv = x @ W_qkv^T  (bf16 out)
  gemm_bt<<<dim3(NQKV / 128, NM / 128), 256, 0, stream>>>(
      xb, wqkvb, nullptr, qkvb, NM, NQKV, NC);
  // 3. qk-norm + rope + v-transpose
  normrope_kernel<<<(NB * NT * NH) / 4, 256, 0, stream>>>(
      qkvb, coords, ttype, qs, ks, qb, kb, vtb);
  // 4. causal attention (paired q-tiles for causal load balance)
  attn_fwd<<<dim3(16, NB * NH), 256, 0, stream>>>(qb, kb, vtb, attnb);
  // 5. out = attn @ W_out^T (fp32 out)
  gemm_bt<<<dim3(NC / 128, NM / 128), 256, 0, stream>>>(
      attnb, woutb, (float*)d_out, nullptr, NM, NC, NC);
}